// Round 1
// 1472.177 us; speedup vs baseline: 1.1491x; 1.1491x over previous
//
#include <hip/hip_runtime.h>
#include <stdint.h>

typedef __bf16 bf16;
typedef __bf16 bf16x8 __attribute__((ext_vector_type(8)));
typedef float f32x4 __attribute__((ext_vector_type(4)));

#define NN 30000
#define NE 300000
#define NG 128
#define DD 128

// ---------------------------------------------------------------------------
// f32-accurate GEMM via 3-term bf16 split: a*b ~= ah*bh + ah*bl + al*bh.
// MODE 0: A = plain f32 [M x K] streamed.
// MODE 1: A streamed; epilogue adds s0[i0[m]*256+n] + s1[i1[m]*256+n]
//         (edge L1: A=eattr, s0=Pr (incl. u-term), s1=Pc, i0=row, i1=col).
// MODE 2: A = [s0[gm] | s1[gm]] concat by K-half (DD each); epilogue adds
//         s2[i2[m]*256+n]  (node L1: s0=nodes, s1=agg, s2=Pun, i2=batch;
//         also Pr build: K=128, s0=nodes, s2=Pu, i2=batch).
// ---------------------------------------------------------------------------
template <int MODE>
__global__ __launch_bounds__(512) void gemm_wide(
    const float* __restrict__ A, const bf16* __restrict__ Bh,
    const bf16* __restrict__ Bl, const float* __restrict__ bias,
    float* __restrict__ C, int M, int K, int do_relu,
    const float* __restrict__ s0, const float* __restrict__ s1,
    const float* __restrict__ s2, const int* __restrict__ i0,
    const int* __restrict__ i1, const int* __restrict__ i2) {
  __shared__ bf16 Ash[128 * 32];
  __shared__ bf16 Asl[128 * 32];
  __shared__ bf16 Bsh[256 * 32];
  __shared__ bf16 Bsl[256 * 32];
  const int tid = threadIdx.x;
  const int w = tid >> 6, lane = tid & 63;
  const int wm = w >> 2, wn = w & 3;  // 2 x 4 waves over 128 x 256
  const int m0 = blockIdx.x * 128;
  const int ar = tid >> 2;        // 0..127: A row / B row pair
  const int k8 = (tid & 3) * 8;   // 0,8,16,24 within 32-wide k-slab

  int gm = m0 + ar;
  if (gm > M - 1) gm = M - 1;  // clamp partial tile; stores guarded below

  f32x4 acc[4][4];
#pragma unroll
  for (int a = 0; a < 4; ++a)
#pragma unroll
    for (int b = 0; b < 4; ++b) acc[a][b] = {0.f, 0.f, 0.f, 0.f};

  for (int k0 = 0; k0 < K; k0 += 32) {
    const float* ga;
    if (MODE == 2) {
      int kk = k0 + k8;
      ga = (kk < DD) ? (s0 + (size_t)gm * DD + kk)
                     : (s1 + (size_t)gm * DD + (kk - DD));
    } else {
      ga = A + (size_t)gm * K + k0 + k8;
    }
    f32x4 a0 = *(const f32x4*)ga;
    f32x4 a1 = *(const f32x4*)(ga + 4);
    bf16x8 vh, vl;
#pragma unroll
    for (int i = 0; i < 4; ++i) {
      float x = a0[i];
      bf16 h = (bf16)x;
      vh[i] = h;
      vl[i] = (bf16)(x - (float)h);
    }
#pragma unroll
    for (int i = 0; i < 4; ++i) {
      float x = a1[i];
      bf16 h = (bf16)x;
      vh[4 + i] = h;
      vl[4 + i] = (bf16)(x - (float)h);
    }
    bf16x8 bh0 = *(const bf16x8*)(Bh + (size_t)ar * K + k0 + k8);
    bf16x8 bl0 = *(const bf16x8*)(Bl + (size_t)ar * K + k0 + k8);
    bf16x8 bh1 = *(const bf16x8*)(Bh + (size_t)(ar + 128) * K + k0 + k8);
    bf16x8 bl1 = *(const bf16x8*)(Bl + (size_t)(ar + 128) * K + k0 + k8);

    __syncthreads();
    *(bf16x8*)&Ash[ar * 32 + k8] = vh;
    *(bf16x8*)&Asl[ar * 32 + k8] = vl;
    *(bf16x8*)&Bsh[ar * 32 + k8] = bh0;
    *(bf16x8*)&Bsl[ar * 32 + k8] = bl0;
    *(bf16x8*)&Bsh[(ar + 128) * 32 + k8] = bh1;
    *(bf16x8*)&Bsl[(ar + 128) * 32 + k8] = bl1;
    __syncthreads();

    const int lr = lane & 15, q8 = (lane >> 4) * 8;
    bf16x8 afh[4], afl[4], bfh[4], bfl[4];
#pragma unroll
    for (int mi = 0; mi < 4; ++mi) {
      afh[mi] = *(const bf16x8*)&Ash[(wm * 64 + mi * 16 + lr) * 32 + q8];
      afl[mi] = *(const bf16x8*)&Asl[(wm * 64 + mi * 16 + lr) * 32 + q8];
    }
#pragma unroll
    for (int ni = 0; ni < 4; ++ni) {
      bfh[ni] = *(const bf16x8*)&Bsh[(wn * 64 + ni * 16 + lr) * 32 + q8];
      bfl[ni] = *(const bf16x8*)&Bsl[(wn * 64 + ni * 16 + lr) * 32 + q8];
    }
#pragma unroll
    for (int mi = 0; mi < 4; ++mi)
#pragma unroll
      for (int ni = 0; ni < 4; ++ni) {
        acc[mi][ni] = __builtin_amdgcn_mfma_f32_16x16x32_bf16(
            afl[mi], bfh[ni], acc[mi][ni], 0, 0, 0);
        acc[mi][ni] = __builtin_amdgcn_mfma_f32_16x16x32_bf16(
            afh[mi], bfl[ni], acc[mi][ni], 0, 0, 0);
        acc[mi][ni] = __builtin_amdgcn_mfma_f32_16x16x32_bf16(
            afh[mi], bfh[ni], acc[mi][ni], 0, 0, 0);
      }
  }

  // C/D layout: col=lane&15, row=(lane>>4)*4+reg  [measured m89/m91]
  const int lr = lane & 15;
  const int rq = (lane >> 4) * 4;
  float bb[4];
#pragma unroll
  for (int ni = 0; ni < 4; ++ni) bb[ni] = bias[wn * 64 + ni * 16 + lr];
#pragma unroll
  for (int mi = 0; mi < 4; ++mi) {
#pragma unroll
    for (int r = 0; r < 4; ++r) {
      int m = m0 + wm * 64 + mi * 16 + rq + r;
      if (m >= M) continue;
      const float* p0 = nullptr;
      const float* p1 = nullptr;
      const float* p2 = nullptr;
      if (MODE == 1) {
        int rv = i0[m], cv = i1[m];
        p0 = s0 + (size_t)rv * 256;
        p1 = s1 + (size_t)cv * 256;
      } else if (MODE == 2) {
        int gv = i2[m];
        p2 = s2 + (size_t)gv * 256;
      }
#pragma unroll
      for (int ni = 0; ni < 4; ++ni) {
        int n = wn * 64 + ni * 16 + lr;
        float v = acc[mi][ni][r] + bb[ni];
        if (MODE == 1) v += p0[n] + p1[n];
        if (MODE == 2) v += p2[n];
        if (do_relu) v = v > 0.f ? v : 0.f;
        C[(size_t)m * 256 + n] = v;
      }
    }
  }
}

// 128x128-tile GEMM, 256 threads, plain f32 A (final N=128 layers).
__global__ __launch_bounds__(256) void gemm128(
    const float* __restrict__ A, const bf16* __restrict__ Bh,
    const bf16* __restrict__ Bl, const float* __restrict__ bias,
    float* __restrict__ C, int M, int N, int K, int do_relu) {
  __shared__ bf16 Ash[128 * 32];
  __shared__ bf16 Asl[128 * 32];
  __shared__ bf16 Bsh[128 * 32];
  __shared__ bf16 Bsl[128 * 32];
  const int tid = threadIdx.x;
  const int w = tid >> 6, lane = tid & 63;
  const int wm = w >> 1, wn = w & 1;
  const int m0 = blockIdx.x * 128, n0 = blockIdx.y * 128;
  const int ar = tid >> 2;
  const int k8 = (tid & 3) * 8;

  int gmA0 = m0 + ar;      if (gmA0 > M - 1) gmA0 = M - 1;
  int gmA1 = m0 + ar + 64; if (gmA1 > M - 1) gmA1 = M - 1;

  f32x4 acc[4][4];
#pragma unroll
  for (int a = 0; a < 4; ++a)
#pragma unroll
    for (int b = 0; b < 4; ++b) acc[a][b] = {0.f, 0.f, 0.f, 0.f};

  for (int k0 = 0; k0 < K; k0 += 32) {
    f32x4 a00 = *(const f32x4*)(A + (size_t)gmA0 * K + k0 + k8);
    f32x4 a01 = *(const f32x4*)(A + (size_t)gmA0 * K + k0 + k8 + 4);
    f32x4 a10 = *(const f32x4*)(A + (size_t)gmA1 * K + k0 + k8);
    f32x4 a11 = *(const f32x4*)(A + (size_t)gmA1 * K + k0 + k8 + 4);
    bf16x8 v0h, v0l, v1h, v1l;
#pragma unroll
    for (int i = 0; i < 4; ++i) {
      float x = a00[i]; bf16 h = (bf16)x; v0h[i] = h; v0l[i] = (bf16)(x - (float)h);
      x = a01[i]; h = (bf16)x; v0h[4 + i] = h; v0l[4 + i] = (bf16)(x - (float)h);
      x = a10[i]; h = (bf16)x; v1h[i] = h; v1l[i] = (bf16)(x - (float)h);
      x = a11[i]; h = (bf16)x; v1h[4 + i] = h; v1l[4 + i] = (bf16)(x - (float)h);
    }
    bf16x8 bh0 = *(const bf16x8*)(Bh + (size_t)(n0 + ar) * K + k0 + k8);
    bf16x8 bl0 = *(const bf16x8*)(Bl + (size_t)(n0 + ar) * K + k0 + k8);
    bf16x8 bh1 = *(const bf16x8*)(Bh + (size_t)(n0 + ar + 64) * K + k0 + k8);
    bf16x8 bl1 = *(const bf16x8*)(Bl + (size_t)(n0 + ar + 64) * K + k0 + k8);

    __syncthreads();
    *(bf16x8*)&Ash[ar * 32 + k8] = v0h;
    *(bf16x8*)&Asl[ar * 32 + k8] = v0l;
    *(bf16x8*)&Ash[(ar + 64) * 32 + k8] = v1h;
    *(bf16x8*)&Asl[(ar + 64) * 32 + k8] = v1l;
    *(bf16x8*)&Bsh[ar * 32 + k8] = bh0;
    *(bf16x8*)&Bsl[ar * 32 + k8] = bl0;
    *(bf16x8*)&Bsh[(ar + 64) * 32 + k8] = bh1;
    *(bf16x8*)&Bsl[(ar + 64) * 32 + k8] = bl1;
    __syncthreads();

    const int lr = lane & 15, q8 = (lane >> 4) * 8;
    bf16x8 afh[4], afl[4], bfh[4], bfl[4];
#pragma unroll
    for (int mi = 0; mi < 4; ++mi) {
      afh[mi] = *(const bf16x8*)&Ash[(wm * 64 + mi * 16 + lr) * 32 + q8];
      afl[mi] = *(const bf16x8*)&Asl[(wm * 64 + mi * 16 + lr) * 32 + q8];
    }
#pragma unroll
    for (int ni = 0; ni < 4; ++ni) {
      bfh[ni] = *(const bf16x8*)&Bsh[(wn * 64 + ni * 16 + lr) * 32 + q8];
      bfl[ni] = *(const bf16x8*)&Bsl[(wn * 64 + ni * 16 + lr) * 32 + q8];
    }
#pragma unroll
    for (int mi = 0; mi < 4; ++mi)
#pragma unroll
      for (int ni = 0; ni < 4; ++ni) {
        acc[mi][ni] = __builtin_amdgcn_mfma_f32_16x16x32_bf16(
            afl[mi], bfh[ni], acc[mi][ni], 0, 0, 0);
        acc[mi][ni] = __builtin_amdgcn_mfma_f32_16x16x32_bf16(
            afh[mi], bfl[ni], acc[mi][ni], 0, 0, 0);
        acc[mi][ni] = __builtin_amdgcn_mfma_f32_16x16x32_bf16(
            afh[mi], bfh[ni], acc[mi][ni], 0, 0, 0);
      }
  }

  const int lr = lane & 15;
  const int rq = (lane >> 4) * 4;
#pragma unroll
  for (int ni = 0; ni < 4; ++ni) {
    int n = n0 + wn * 64 + ni * 16 + lr;
    float bb = bias[n];
#pragma unroll
    for (int mi = 0; mi < 4; ++mi) {
#pragma unroll
      for (int r = 0; r < 4; ++r) {
        int m = m0 + wm * 64 + mi * 16 + rq + r;
        if (m < M) {
          float v = acc[mi][ni][r] + bb;
          if (do_relu) v = v > 0.f ? v : 0.f;
          C[(size_t)m * N + n] = v;
        }
      }
    }
  }
}

__global__ void splitw_k(const float* __restrict__ W, bf16* __restrict__ Wh,
                         bf16* __restrict__ Wl, int K, int N) {
  int i = blockIdx.x * 256 + threadIdx.x;
  if (i < K * N) {
    int k = i / N, n = i % N;
    float x = W[i];
    bf16 h = (bf16)x;
    Wh[(size_t)n * K + k] = h;
    Wl[(size_t)n * K + k] = (bf16)(x - (float)h);
  }
}

// ---------------------------------------------------------------------------
// Aggregation, contention-split (unchanged).
// ---------------------------------------------------------------------------
#define CHUNK 1024
__global__ __launch_bounds__(256) void agg_scatter_k(
    const float* __restrict__ eout, const int* __restrict__ row,
    const int* __restrict__ col, const int* __restrict__ batch,
    float* __restrict__ agg_sum, float* __restrict__ eg_final) {
  __shared__ float part[NG * 64];  // 32 KB
  const int tid = threadIdx.x;
  const int dg = blockIdx.y;        // dim half: 0 or 1
  const int base = blockIdx.x * CHUNK;
  for (int i = tid; i < NG * 64; i += 256) part[i] = 0.f;
  __syncthreads();

  const int es = tid >> 5;        // 0..7: edge sub-index within iter
  const int dl = tid & 31;        // dim lane
  for (int it = 0; it < CHUNK / 8; ++it) {
    int e = base + it * 8 + es;
    if (e < NE) {
      int c = col[e];
      int g = batch[row[e]];
      const float* ep = eout + (size_t)e * 128 + dg * 64 + dl;
      float v0 = ep[0];
      float v1 = ep[32];
      atomicAdd(&agg_sum[(size_t)c * 128 + dg * 64 + dl], v0);
      atomicAdd(&agg_sum[(size_t)c * 128 + dg * 64 + dl + 32], v1);
      atomicAdd(&part[g * 64 + dl], v0);
      atomicAdd(&part[g * 64 + dl + 32], v1);
    }
  }
  __syncthreads();
  for (int i = tid; i < NG * 64; i += 256) {
    int g = i >> 6, dd = i & 63;
    atomicAdd(&eg_final[g * 128 + dg * 64 + dd], part[i]);
  }
}

__global__ __launch_bounds__(256) void cnt_k(const int* __restrict__ row,
                                             const int* __restrict__ col,
                                             const int* __restrict__ batch,
                                             float* __restrict__ cnt_node,
                                             float* __restrict__ cnt_ge) {
  __shared__ float hist[NG];
  const int tid = threadIdx.x;
  if (tid < NG) hist[tid] = 0.f;
  __syncthreads();
  for (int e = blockIdx.x * 256 + tid; e < NE; e += gridDim.x * 256) {
    atomicAdd(&cnt_node[col[e]], 1.f);
    atomicAdd(&hist[batch[row[e]]], 1.f);
  }
  __syncthreads();
  if (tid < NG) atomicAdd(&cnt_ge[tid], hist[tid]);
}

__global__ void agg_fin_k(float* __restrict__ agg_sum,
                          const float* __restrict__ cnt_node) {
  int i = blockIdx.x * 256 + threadIdx.x;
  if (i < NN * 128) {
    float c = cnt_node[i >> 7];
    c = c > 1.f ? c : 1.f;
    agg_sum[i] = agg_sum[i] / c;
  }
}

__global__ void node_gagg_k(const float* __restrict__ nout,
                            const int* __restrict__ batch,
                            float* __restrict__ ngsum,
                            float* __restrict__ cnt_gn) {
  int n = blockIdx.x, d = threadIdx.x;
  int g = batch[n];
  float v = nout[(size_t)n * 128 + d];
  atomicAdd(&ngsum[((size_t)(n & 63) * 128 + g) * 128 + d], v);
  if (d == 0) atomicAdd(&cnt_gn[g], 1.f);
}

__global__ void gin_k(const float* __restrict__ ngsum,
                      const float* __restrict__ eg_final,
                      const float* __restrict__ cnt_gn,
                      const float* __restrict__ cnt_ge,
                      const float* __restrict__ u, float* __restrict__ g_in) {
  int g = blockIdx.x, d = threadIdx.x;
  float ns = 0.f;
  for (int r = 0; r < 64; ++r) ns += ngsum[((size_t)r * 128 + g) * 128 + d];
  float es = eg_final[g * 128 + d];
  float cn = cnt_gn[g]; cn = cn > 1.f ? cn : 1.f;
  float ce = cnt_ge[g]; ce = ce > 1.f ? ce : 1.f;
  g_in[g * 384 + d] = u[g * 128 + d];
  g_in[g * 384 + 128 + d] = ns / cn;
  g_in[g * 384 + 256 + d] = es / ce;
}

extern "C" void kernel_launch(void* const* d_in, const int* in_sizes, int n_in,
                              void* d_out, int out_size, void* d_ws,
                              size_t ws_size, hipStream_t stream) {
  (void)in_sizes; (void)n_in; (void)out_size; (void)ws_size;
  const float* nodes = (const float*)d_in[0];
  const int* eidx = (const int*)d_in[1];
  const float* eattr = (const float*)d_in[2];
  const float* u = (const float*)d_in[3];
  const int* batch = (const int*)d_in[4];
  const float* W[9] = {(const float*)d_in[5],  (const float*)d_in[7],
                       (const float*)d_in[9],  (const float*)d_in[11],
                       (const float*)d_in[13], (const float*)d_in[15],
                       (const float*)d_in[17], (const float*)d_in[19],
                       (const float*)d_in[21]};
  const float* Bi[9] = {(const float*)d_in[6],  (const float*)d_in[8],
                        (const float*)d_in[10], (const float*)d_in[12],
                        (const float*)d_in[14], (const float*)d_in[16],
                        (const float*)d_in[18], (const float*)d_in[20],
                        (const float*)d_in[22]};
  const int* row = eidx;
  const int* col = eidx + NE;

  char* p = (char*)d_ws;
  auto alloc = [&](size_t b) {
    void* r = (void*)p;
    p += (b + 255) & ~(size_t)255;
    return r;
  };
  float* h_e0 = (float*)alloc((size_t)NE * 256 * 4);  // f32 hidden, in-place L1

  // Weight slices (pre-split, transposed to [n][k]):
  //  0: W0[  0:128)  (-> Pr via nodes)      1: W0[128:256) (-> Pc via nodes)
  //  2: W0[256:384)  (edge L1 A-part)       3: W0[384:512) (-> Pu via u)
  //  4: W1            5: W2
  //  6: W3[  0:256)  (node L1 [nodes|agg])  7: W3[256:384) (-> Pun via u)
  //  8: W4            9: W5
  // 10: W6           11: W7                12: W8
  const int wk[13] = {128, 128, 128, 128, 256, 256, 256, 128, 256, 256, 384, 256, 256};
  const int wnn[13] = {256, 256, 256, 256, 256, 128, 256, 256, 256, 128, 256, 256, 128};
  const float* Wsrc[13] = {W[0],              W[0] + 128 * 256, W[0] + 256 * 256,
                           W[0] + 384 * 256,  W[1],             W[2],
                           W[3],              W[3] + 256 * 256, W[4],
                           W[5],              W[6],             W[7],
                           W[8]};
  bf16 *Wh[13], *Wl[13];
  for (int i = 0; i < 13; ++i) {
    Wh[i] = (bf16*)alloc((size_t)wk[i] * wnn[i] * 2);
    Wl[i] = (bf16*)alloc((size_t)wk[i] * wnn[i] * 2);
  }

  // Projection tables
  float* Pu = (float*)alloc((size_t)NG * 256 * 4);   // u @ W0d
  float* Pr = (float*)alloc((size_t)NN * 256 * 4);   // nodes @ W0a + Pu[batch]
  float* Pc = (float*)alloc((size_t)NN * 256 * 4);   // nodes @ W0b
  float* Pun = (float*)alloc((size_t)NG * 256 * 4);  // u @ W3c

  char* zero_base = p;
  float* agg_sum = (float*)alloc((size_t)NN * 128 * 4);
  float* cnt_node = (float*)alloc((size_t)NN * 4);
  float* ngsum = (float*)alloc((size_t)64 * 128 * 128 * 4);
  float* eg_final = (float*)alloc((size_t)NG * 128 * 4);
  float* cnt_gn = (float*)alloc(512);
  float* cnt_ge = (float*)alloc(512);
  float* zeros = (float*)alloc(256 * 4);  // zero bias for projection GEMMs
  size_t zero_len = (size_t)(p - zero_base);
  float* g_in = (float*)alloc((size_t)NG * 384 * 4);
  float* h_g0 = (float*)alloc((size_t)NG * 256 * 4);
  float* h_n0 = h_e0;

  float* out_nodes = (float*)d_out;
  float* out_edges = out_nodes + (size_t)NN * 128;
  float* out_glob = out_nodes + (size_t)NN * 128 + (size_t)NE * 128;

  for (int i = 0; i < 13; ++i) {
    int tot = wk[i] * wnn[i];
    splitw_k<<<(tot + 255) / 256, 256, 0, stream>>>(Wsrc[i], Wh[i], Wl[i],
                                                    wk[i], wnn[i]);
  }
  hipMemsetAsync(zero_base, 0, zero_len, stream);

  const int gbE = (NE + 127) / 128;   // 2344
  const int gbN = (NN + 127) / 128;   // 235

  // ---- Projections (K=128 each) ----
  // Pu = u @ W0d   (128 rows, one block)
  gemm_wide<0><<<1, 512, 0, stream>>>(u, Wh[3], Wl[3], zeros, Pu, NG, 128, 0,
                                      nullptr, nullptr, nullptr, nullptr,
                                      nullptr, nullptr);
  // Pr = nodes @ W0a + Pu[batch[v]]   (MODE 2, K=128 -> s0 only)
  gemm_wide<2><<<gbN, 512, 0, stream>>>(nullptr, Wh[0], Wl[0], zeros, Pr, NN,
                                        128, 0, nodes, nullptr, Pu, nullptr,
                                        nullptr, batch);
  // Pc = nodes @ W0b
  gemm_wide<0><<<gbN, 512, 0, stream>>>(nodes, Wh[1], Wl[1], zeros, Pc, NN,
                                        128, 0, nullptr, nullptr, nullptr,
                                        nullptr, nullptr, nullptr);
  // Pun = u @ W3c
  gemm_wide<0><<<1, 512, 0, stream>>>(u, Wh[7], Wl[7], zeros, Pun, NG, 128, 0,
                                      nullptr, nullptr, nullptr, nullptr,
                                      nullptr, nullptr);

  // ---- Edge MLP: (eattr @ W0c + Pr[row] + Pc[col] + b0) -> 256 -> 128 ----
  gemm_wide<1><<<gbE, 512, 0, stream>>>(eattr, Wh[2], Wl[2], Bi[0], h_e0, NE,
                                        128, 1, Pr, Pc, nullptr, row, col,
                                        nullptr);
  gemm_wide<0><<<gbE, 512, 0, stream>>>(h_e0, Wh[4], Wl[4], Bi[1], h_e0, NE,
                                        256, 1, nullptr, nullptr, nullptr,
                                        nullptr, nullptr, nullptr);
  gemm128<<<dim3(gbE, 1), 256, 0, stream>>>(h_e0, Wh[5], Wl[5], Bi[2],
                                            out_edges, NE, 128, 256, 0);

  // Aggregations (contention-split)
  agg_scatter_k<<<dim3((NE + CHUNK - 1) / CHUNK, 2), 256, 0, stream>>>(
      out_edges, row, col, batch, agg_sum, eg_final);
  cnt_k<<<128, 256, 0, stream>>>(row, col, batch, cnt_node, cnt_ge);
  agg_fin_k<<<(NN * 128 + 255) / 256, 256, 0, stream>>>(agg_sum, cnt_node);

  // ---- Node MLP: ([nodes|agg] @ W3ab + Pun[batch] + b3) -> 256 -> 128 ----
  gemm_wide<2><<<gbN, 512, 0, stream>>>(nullptr, Wh[6], Wl[6], Bi[3], h_n0, NN,
                                        256, 1, nodes, agg_sum, Pun, nullptr,
                                        nullptr, batch);
  gemm_wide<0><<<gbN, 512, 0, stream>>>(h_n0, Wh[8], Wl[8], Bi[4], h_n0, NN,
                                        256, 1, nullptr, nullptr, nullptr,
                                        nullptr, nullptr, nullptr);
  gemm128<<<dim3(gbN, 1), 256, 0, stream>>>(h_n0, Wh[9], Wl[9], Bi[5],
                                            out_nodes, NN, 128, 256, 0);

  node_gagg_k<<<NN, 128, 0, stream>>>(out_nodes, batch, ngsum, cnt_gn);
  gin_k<<<NG, 128, 0, stream>>>(ngsum, eg_final, cnt_gn, cnt_ge, u, g_in);

  // ---- Global MLP: 384 -> 256 -> 256 -> 128 ----
  gemm_wide<0><<<1, 512, 0, stream>>>(g_in, Wh[10], Wl[10], Bi[6], h_g0, NG,
                                      384, 1, nullptr, nullptr, nullptr,
                                      nullptr, nullptr, nullptr);
  gemm_wide<0><<<1, 512, 0, stream>>>(h_g0, Wh[11], Wl[11], Bi[7], h_g0, NG,
                                      256, 1, nullptr, nullptr, nullptr,
                                      nullptr, nullptr, nullptr);
  gemm128<<<dim3(1, 1), 256, 0, stream>>>(h_g0, Wh[12], Wl[12], Bi[8],
                                          out_glob, NG, 128, 256, 0);
}